// Round 5
// baseline (178.877 us; speedup 1.0000x reference)
//
#include <hip/hip_runtime.h>

#define TT 512   // timesteps
#define ID 32    // input features
#define HD 64    // hidden
#define NTK 8    // tickers

typedef __attribute__((ext_vector_type(8))) _Float16 half8;
typedef __attribute__((ext_vector_type(4))) float f32x4;

// Pre-pass: x f32 -> f16 (one half8 per thread)
__global__ void cvt_x(const float* __restrict__ x, _Float16* __restrict__ xo, int n8) {
    int i = blockIdx.x * blockDim.x + threadIdx.x;
    if (i >= n8) return;
    const float4* p = (const float4*)x + 2 * (size_t)i;
    float4 a = p[0], b = p[1];
    half8 o = {(_Float16)a.x, (_Float16)a.y, (_Float16)a.z, (_Float16)a.w,
               (_Float16)b.x, (_Float16)b.y, (_Float16)b.z, (_Float16)b.w};
    *((half8*)xo + i) = o;
}

// 256 blocks x 512 threads (8 waves = 2/SIMD), 2 batch rows per block.
// Gate-INTERLEAVED weight permutation: col 4j+g = gate g of hidden unit j,
// pre-scaled by s_g (-log2e for sigmoid gates, +2log2e for tanh) so the
// activation is the uniform per-lane affine  act = fma(b_g, rcp(1+exp2(acc)), a_g).
// Wave w owns n-tiles {2w, 2w+1} (hidden units 8w..8w+8, all 4 gates) ->
// 6 MFMA/wave/step. A rows: 0-7 = batch row 0, 8-15 = row 1 (8x duplication).
// Lane (lq,l15): C batch row = lq>>1; lq&1 selects which n-tile it activates,
// so each act value is computed exactly once per duplicate pair.
template <bool XF16>
__global__ __launch_bounds__(512, 2) void lstm_mfma3(
    const float* __restrict__ x,       // (B, T, I) f32 (fallback)
    const _Float16* __restrict__ xf,   // (B, T, I) f16 (fast path)
    const float* __restrict__ w_ih,    // (4H, I)
    const float* __restrict__ w_hh,    // (4H, H)
    const float* __restrict__ b_ih,    // (4H)
    const float* __restrict__ b_hh,    // (4H)
    const float* __restrict__ w_fc,    // (NTK, H)
    const float* __restrict__ b_fc,    // (NTK)
    float* __restrict__ out)           // (B, NTK)
{
    const int tid = threadIdx.x;
    const int wv  = tid >> 6;          // wave 0..7
    const int l   = tid & 63;
    const int l15 = l & 15;
    const int lq  = l >> 4;            // 0..3
    const int r0  = blockIdx.x * 2;

    const int g     = l15 & 3;         // gate slot of this lane's column
    const int jq    = l15 >> 2;        // hidden-unit offset within tile (0..3)
    const int abr   = l15 >> 3;        // A-fragment batch row (0/1)
    const int myrow = lq >> 1;         // C batch row this lane activates
    const int mynt  = lq & 1;          // which of the 2 n-tiles this lane activates

    __shared__ __align__(16) _Float16 zbuf[2][2][HD];  // [buf][row][hidden]

    // per-gate activation constants (sigmoid: e; tanh: 1-2e)
    const float s  = (g == 2) ? 2.88539008178f : -1.44269504089f;
    const float ab = (g == 2) ? 1.0f : 0.0f;
    const float bb = (g == 2) ? -2.0f : 1.0f;

    // B fragments: col n = lane&15 within tile, k = (lane>>4)*8 + j.
    // Permuted col (tile*16 + l15) -> original W row g*HD + (tile*4 + jq), scaled by s.
    half8 Bf[2][3];
    f32x4 biasC[2];
    #pragma unroll
    for (int nt = 0; nt < 2; ++nt) {
        const int tile = 2 * wv + nt;
        const int grow = g * HD + tile * 4 + jq;     // original gate row
        const float bias = s * (b_ih[grow] + b_hh[grow]);
        biasC[nt] = (f32x4){bias, bias, bias, bias};
        #pragma unroll
        for (int kt = 0; kt < 3; ++kt) {
            const float* src = (kt < 2) ? (w_hh + grow * HD + kt * 32 + lq * 8)
                                        : (w_ih + grow * ID + lq * 8);
            float4 p0 = ((const float4*)src)[0];
            float4 p1 = ((const float4*)src)[1];
            Bf[nt][kt] = (half8){(_Float16)(s*p0.x), (_Float16)(s*p0.y),
                                 (_Float16)(s*p0.z), (_Float16)(s*p0.w),
                                 (_Float16)(s*p1.x), (_Float16)(s*p1.y),
                                 (_Float16)(s*p1.z), (_Float16)(s*p1.w)};
        }
    }

    if (tid < 2 * HD) ((_Float16*)zbuf[0])[tid] = (_Float16)0.0f;

    // x: lane's A-row chunk x[r0+abr][t][lq*8 .. +8), pointer-incremented
    const _Float16* xp = xf + ((size_t)(r0 + abr) * TT) * ID + lq * 8;
    const float*    xq = x  + ((size_t)(r0 + abr) * TT) * ID + lq * 8;
    half8 xa;
    if (XF16) {
        xa = *(const half8*)xp;
    } else {
        float4 a = ((const float4*)xq)[0], b = ((const float4*)xq)[1];
        xa = (half8){(_Float16)a.x, (_Float16)a.y, (_Float16)a.z, (_Float16)a.w,
                     (_Float16)b.x, (_Float16)b.y, (_Float16)b.z, (_Float16)b.w};
    }

    float c_ = 0.0f;
    __syncthreads();

    for (int t = 0; t < TT; ++t) {
        const int cur = t & 1;

        half8 A2 = xa;
        // prefetch next x (pointer add, no mul)
        if (t + 1 < TT) { xp += ID; xq += ID; }
        if (XF16) {
            xa = *(const half8*)xp;
        } else {
            float4 a = ((const float4*)xq)[0], b = ((const float4*)xq)[1];
            xa = (half8){(_Float16)a.x, (_Float16)a.y, (_Float16)a.z, (_Float16)a.w,
                         (_Float16)b.x, (_Float16)b.y, (_Float16)b.z, (_Float16)b.w};
        }

        // h fragments (x-MFMAs below issue under this ds_read latency)
        half8 A0 = *(const half8*)&zbuf[cur][abr][lq * 8];
        half8 A1 = *(const half8*)&zbuf[cur][abr][32 + lq * 8];

        f32x4 acc0 = __builtin_amdgcn_mfma_f32_16x16x32_f16(A2, Bf[0][2], biasC[0], 0, 0, 0);
        f32x4 acc1 = __builtin_amdgcn_mfma_f32_16x16x32_f16(A2, Bf[1][2], biasC[1], 0, 0, 0);
        acc0 = __builtin_amdgcn_mfma_f32_16x16x32_f16(A0, Bf[0][0], acc0, 0, 0, 0);
        acc1 = __builtin_amdgcn_mfma_f32_16x16x32_f16(A0, Bf[1][0], acc1, 0, 0, 0);
        acc0 = __builtin_amdgcn_mfma_f32_16x16x32_f16(A1, Bf[0][1], acc0, 0, 0, 0);
        acc1 = __builtin_amdgcn_mfma_f32_16x16x32_f16(A1, Bf[1][1], acc1, 0, 0, 0);

        // this lane activates one value: n-tile mynt, C reg 0 (row lq*4 -> batch myrow)
        const float pre = mynt ? acc1[0] : acc0[0];
        const float e   = __builtin_amdgcn_rcpf(1.0f + __builtin_amdgcn_exp2f(pre));
        const float act = fmaf(bb, e, ab);

        // gather i,f,g,o of this lane's hidden unit from its 4-lane group
        const int base = l & ~3;
        const float ig = __shfl(act, base + 0);
        const float fg = __shfl(act, base + 1);
        const float gg = __shfl(act, base + 2);
        const float og = __shfl(act, base + 3);
        c_ = fmaf(fg, c_, ig * gg);
        const float th = fmaf(-2.0f,
            __builtin_amdgcn_rcpf(1.0f + __builtin_amdgcn_exp2f(2.88539008178f * c_)), 1.0f);
        const float h_ = og * th;

        if (g == 0) {   // one writer per (row, hidden unit)
            const int j = (2 * wv + mynt) * 4 + jq;
            zbuf[cur ^ 1][myrow][j] = (_Float16)h_;
        }
        __syncthreads();
    }

    // h(T) is in zbuf[0] (last write: t=511, cur=1, wrote buf 0).
    // FC head: waves 0-1 -> rows 0-1; lane: tk=(tid>>3)&7 ticker, q=tid&7 chunk.
    if (tid < 128) {
        const int rr = tid >> 6;
        const int tk = (tid >> 3) & 7;
        const int q  = tid & 7;
        const float* wf = w_fc + tk * HD + q * 8;
        float a = 0.0f;
        #pragma unroll
        for (int m = 0; m < 8; ++m)
            a = fmaf((float)zbuf[0][rr][q * 8 + m], wf[m], a);
        a += __shfl_xor(a, 1);
        a += __shfl_xor(a, 2);
        a += __shfl_xor(a, 4);
        if (q == 0) out[(r0 + rr) * NTK + tk] = a + b_fc[tk];
    }
}

extern "C" void kernel_launch(void* const* d_in, const int* in_sizes, int n_in,
                              void* d_out, int out_size, void* d_ws, size_t ws_size,
                              hipStream_t stream) {
    const float* x    = (const float*)d_in[0];
    const float* w_ih = (const float*)d_in[1];
    const float* w_hh = (const float*)d_in[2];
    const float* b_ih = (const float*)d_in[3];
    const float* b_hh = (const float*)d_in[4];
    const float* w_fc = (const float*)d_in[5];
    const float* b_fc = (const float*)d_in[6];
    float* out = (float*)d_out;

    const int nx = in_sizes[0];              // B*T*I
    const int B  = nx / (TT * ID);           // 512
    const size_t need = (size_t)nx * sizeof(_Float16);

    if (ws_size >= need) {
        _Float16* xf = (_Float16*)d_ws;
        const int n8 = nx / 8;
        cvt_x<<<dim3((n8 + 255) / 256), dim3(256), 0, stream>>>(x, xf, n8);
        lstm_mfma3<true><<<dim3(B / 2), dim3(512), 0, stream>>>(x, xf, w_ih, w_hh,
                                                                b_ih, b_hh, w_fc, b_fc, out);
    } else {
        lstm_mfma3<false><<<dim3(B / 2), dim3(512), 0, stream>>>(x, (const _Float16*)d_ws,
                                                                 w_ih, w_hh, b_ih, b_hh,
                                                                 w_fc, b_fc, out);
    }
}